// Round 1
// baseline (14384.497 us; speedup 1.0000x reference)
//
#include <hip/hip_runtime.h>

#define B_ 64
#define S_ 512
#define D_ 512
#define H_ 1024

typedef __attribute__((ext_vector_type(8))) short bf16x8;
typedef __attribute__((ext_vector_type(4))) float f32x4;
typedef unsigned short u16;
typedef unsigned int u32;

#define MFMA(a, b, c) __builtin_amdgcn_mfma_f32_16x16x32_bf16(a, b, c, 0, 0, 0)

__device__ __forceinline__ u16 f2bf(float f) {
    u32 u = __float_as_uint(f);
    u += 0x7fffu + ((u >> 16) & 1u);
    return (u16)(u >> 16);
}

__device__ __forceinline__ float sigm(float x) { return 1.0f / (1.0f + __expf(-x)); }
__device__ __forceinline__ float tanh_f(float x) { return 1.0f - 2.0f / (__expf(2.0f * x) + 1.0f); }

// ---------------- prep: fp32 weights -> bf16 concatenated [Wih | Whh], K-contiguous ----
__global__ void prep_w(const float* __restrict__ Wih, const float* __restrict__ Whh,
                       u16* __restrict__ Wc, int Kx, int Kw, int total8) {
    int idx = blockIdx.x * 256 + threadIdx.x;
    if (idx >= total8) return;
    int kc8 = Kw >> 3;
    int n = idx / kc8;
    int kc = (idx - n * kc8) << 3;
    const float* src = (kc < Kx) ? (Wih + (size_t)n * Kx + kc)
                                 : (Whh + (size_t)n * (Kw - Kx) + (kc - Kx));
    float4 f0 = ((const float4*)src)[0];
    float4 f1 = ((const float4*)src)[1];
    bf16x8 v;
    v[0] = (short)f2bf(f0.x); v[1] = (short)f2bf(f0.y);
    v[2] = (short)f2bf(f0.z); v[3] = (short)f2bf(f0.w);
    v[4] = (short)f2bf(f1.x); v[5] = (short)f2bf(f1.y);
    v[6] = (short)f2bf(f1.z); v[7] = (short)f2bf(f1.w);
    *(bf16x8*)(Wc + (size_t)n * Kw + kc) = v;
}

// ---------------- prep: biases + initial state ----------------
__global__ void prep_misc(const float* __restrict__ h0in, const float* __restrict__ c0in,
                          const float* __restrict__ bih0, const float* __restrict__ bhh0,
                          const float* __restrict__ bih1, const float* __restrict__ bhh1,
                          float* __restrict__ bias0, float* __restrict__ bias1,
                          u16* __restrict__ h0A, u16* __restrict__ h0B,
                          u16* __restrict__ h1A, u16* __restrict__ h1B,
                          float* __restrict__ c0, float* __restrict__ c1,
                          float* __restrict__ h1f) {
    int idx = blockIdx.x * 256 + threadIdx.x;
    if (idx < 4096) { bias0[idx] = bih0[idx] + bhh0[idx]; return; }
    if (idx < 8192) { int i = idx - 4096; bias1[i] = bih1[i] + bhh1[i]; return; }
    int r2 = idx - 8192;
    if (r2 >= 2 * B_ * H_) return;
    int l = r2 >> 16;          // B_*H_ = 65536
    int r = r2 & 65535;
    float hv = h0in[r2];
    float cv = c0in[r2];
    u16 hb = f2bf(hv);
    if (l == 0) { h0A[r] = hb; h0B[r] = hb; c0[r] = cv; }
    else        { h1A[r] = hb; h1B[r] = hb; c1[r] = cv; h1f[r] = hv; }
}

// ---------------- one pipeline phase: layer0 @ step t, layer1 @ step t-1 ----------------
// 256 blocks: [0,128) layer0, [128,256) layer1; each block: 8 h-cols -> 32 gate cols,
// 256 threads = 4 waves, wave w = batch rows 16w..16w+15 x 32 gate cols (2 MFMA N-tiles).
__global__ __launch_bounds__(256) void phase_k(
    const float* __restrict__ x, int t,
    const u16* __restrict__ W0, const u16* __restrict__ W1,
    const float* __restrict__ bias0, const float* __restrict__ bias1,
    const u16* __restrict__ h0r, u16* __restrict__ h0w,
    const u16* __restrict__ h1r, u16* __restrict__ h1w,
    float* __restrict__ c0, float* __restrict__ c1,
    float* __restrict__ h1f,
    int do0, int do1) {
    const int layer = blockIdx.x >> 7;
    if (layer ? !do1 : !do0) return;
    const int hc0 = (blockIdx.x & 127) << 3;
    const int tid = threadIdx.x;
    const int wave = tid >> 6, lane = tid & 63;
    const int quad = lane >> 4, l16 = lane & 15;
    const int arow = wave * 16 + l16;      // batch row for A fragment
    const int koff = quad * 8;             // K offset for this lane's fragment

    const int Kw = layer ? 2048 : 1536;
    const int g0 = l16 >> 3;               // gate pair selector within tile
    const int nc = hc0 + (l16 & 7);
    const u16* Wb = layer ? W1 : W0;
    const u16* wt0 = Wb + (size_t)((g0)*1024 + nc) * Kw + koff;       // gates i/f
    const u16* wt1 = Wb + (size_t)((g0 + 2) * 1024 + nc) * Kw + koff; // gates g/o

    f32x4 acc0 = {0.f, 0.f, 0.f, 0.f};
    f32x4 acc1 = {0.f, 0.f, 0.f, 0.f};

    if (layer == 0) {
        // segment 1: x_t (fp32 -> bf16 on the fly), K = 0..511
        const float* xr = x + ((size_t)arow * S_ + t) * D_ + koff;
        #pragma unroll 4
        for (int k = 0; k < 512; k += 32) {
            float4 f0 = ((const float4*)(xr + k))[0];
            float4 f1 = ((const float4*)(xr + k))[1];
            bf16x8 a;
            a[0] = (short)f2bf(f0.x); a[1] = (short)f2bf(f0.y);
            a[2] = (short)f2bf(f0.z); a[3] = (short)f2bf(f0.w);
            a[4] = (short)f2bf(f1.x); a[5] = (short)f2bf(f1.y);
            a[6] = (short)f2bf(f1.z); a[7] = (short)f2bf(f1.w);
            bf16x8 b0 = *(const bf16x8*)(wt0 + k);
            bf16x8 b1 = *(const bf16x8*)(wt1 + k);
            acc0 = MFMA(a, b0, acc0);
            acc1 = MFMA(a, b1, acc1);
        }
        // segment 2: h0_prev (bf16), K = 512..1535
        const u16* hr = h0r + arow * H_ + koff;
        const u16* w0b = wt0 + 512;
        const u16* w1b = wt1 + 512;
        #pragma unroll 4
        for (int k = 0; k < 1024; k += 32) {
            bf16x8 a = *(const bf16x8*)(hr + k);
            bf16x8 b0 = *(const bf16x8*)(w0b + k);
            bf16x8 b1 = *(const bf16x8*)(w1b + k);
            acc0 = MFMA(a, b0, acc0);
            acc1 = MFMA(a, b1, acc1);
        }
    } else {
        // segment 1: input = h0 (state after phase p-1), K = 0..1023
        const u16* hr0 = h0r + arow * H_ + koff;
        #pragma unroll 4
        for (int k = 0; k < 1024; k += 32) {
            bf16x8 a = *(const bf16x8*)(hr0 + k);
            bf16x8 b0 = *(const bf16x8*)(wt0 + k);
            bf16x8 b1 = *(const bf16x8*)(wt1 + k);
            acc0 = MFMA(a, b0, acc0);
            acc1 = MFMA(a, b1, acc1);
        }
        // segment 2: h1_prev, K = 1024..2047
        const u16* hr1 = h1r + arow * H_ + koff;
        const u16* w0b = wt0 + 1024;
        const u16* w1b = wt1 + 1024;
        #pragma unroll 4
        for (int k = 0; k < 1024; k += 32) {
            bf16x8 a = *(const bf16x8*)(hr1 + k);
            bf16x8 b0 = *(const bf16x8*)(w0b + k);
            bf16x8 b1 = *(const bf16x8*)(w1b + k);
            acc0 = MFMA(a, b0, acc0);
            acc1 = MFMA(a, b1, acc1);
        }
    }

    // epilogue: gates -> LDS (stride 36 floats: 2-way-only bank aliasing), add bias
    __shared__ float lds[64 * 36];
    const float* bias = layer ? bias1 : bias0;
    float bv0 = bias[(g0)*1024 + nc];
    float bv1 = bias[(g0 + 2) * 1024 + nc];
    #pragma unroll
    for (int r = 0; r < 4; ++r) {
        int row = wave * 16 + quad * 4 + r;   // C/D layout: row=(lane>>4)*4+reg, col=lane&15
        lds[row * 36 + l16]      = acc0[r] + bv0;
        lds[row * 36 + 16 + l16] = acc1[r] + bv1;
    }
    __syncthreads();

    // cell update: cols [0..7]=i, [8..15]=f, [16..23]=g, [24..31]=o for h-cols hc0..hc0+7
    const int j = tid & 7;
    const int bb = tid >> 3;   // 0..31
    float* cptr = layer ? c1 : c0;
    #pragma unroll
    for (int rep = 0; rep < 2; ++rep) {
        int b = bb + rep * 32;
        float gi = lds[b * 36 + j];
        float gf = lds[b * 36 + 8 + j];
        float gg = lds[b * 36 + 16 + j];
        float go = lds[b * 36 + 24 + j];
        int cidx = b * H_ + hc0 + j;
        float cold = cptr[cidx];
        float cn = sigm(gf) * cold + sigm(gi) * tanh_f(gg);
        float hn = sigm(go) * tanh_f(cn);
        cptr[cidx] = cn;
        u16 hb = f2bf(hn);
        if (layer) { h1w[cidx] = hb; h1f[cidx] = hn; }
        else       { h0w[cidx] = hb; }
    }
}

// ---------------- final FC: out[b,o] = h1 . Wfc[o] + bfc[o] ----------------
__global__ void fc_k(const float* __restrict__ h1f, const float* __restrict__ Wfc,
                     const float* __restrict__ bfc, float* __restrict__ out) {
    int idx = blockIdx.x * 256 + threadIdx.x;
    if (idx >= 64 * 1000) return;
    int o = idx % 1000;
    int b = idx / 1000;
    const float4* hr = (const float4*)(h1f + b * H_);
    const float4* wr = (const float4*)(Wfc + (size_t)o * H_);
    float s = 0.f;
    #pragma unroll 4
    for (int k = 0; k < 256; ++k) {
        float4 a = hr[k];
        float4 w = wr[k];
        s += a.x * w.x + a.y * w.y + a.z * w.z + a.w * w.w;
    }
    out[idx] = s + bfc[o];
}

extern "C" void kernel_launch(void* const* d_in, const int* in_sizes, int n_in,
                              void* d_out, int out_size, void* d_ws, size_t ws_size,
                              hipStream_t stream) {
    const float* x    = (const float*)d_in[0];
    const float* h0in = (const float*)d_in[1];
    const float* c0in = (const float*)d_in[2];
    const float* Wih0 = (const float*)d_in[3];
    const float* Whh0 = (const float*)d_in[4];
    const float* bih0 = (const float*)d_in[5];
    const float* bhh0 = (const float*)d_in[6];
    const float* Wih1 = (const float*)d_in[7];
    const float* Whh1 = (const float*)d_in[8];
    const float* bih1 = (const float*)d_in[9];
    const float* bhh1 = (const float*)d_in[10];
    const float* Wfc  = (const float*)d_in[11];
    const float* bfc  = (const float*)d_in[12];
    float* out = (float*)d_out;

    char* ws = (char*)d_ws;
    size_t off = 0;
    auto alloc = [&](size_t bytes) {
        void* p = ws + off;
        off += (bytes + 255) & ~(size_t)255;
        return p;
    };
    u16* W0    = (u16*)alloc((size_t)4096 * 1536 * 2);
    u16* W1    = (u16*)alloc((size_t)4096 * 2048 * 2);
    float* bias0 = (float*)alloc(4096 * 4);
    float* bias1 = (float*)alloc(4096 * 4);
    u16* h0A   = (u16*)alloc(B_ * H_ * 2);
    u16* h0B   = (u16*)alloc(B_ * H_ * 2);
    u16* h1A   = (u16*)alloc(B_ * H_ * 2);
    u16* h1B   = (u16*)alloc(B_ * H_ * 2);
    float* c0  = (float*)alloc(B_ * H_ * 4);
    float* c1  = (float*)alloc(B_ * H_ * 4);
    float* h1f = (float*)alloc(B_ * H_ * 4);

    prep_w<<<786432 / 256, 256, 0, stream>>>(Wih0, Whh0, W0, 512, 1536, 786432);
    prep_w<<<1048576 / 256, 256, 0, stream>>>(Wih1, Whh1, W1, 1024, 2048, 1048576);
    prep_misc<<<(8192 + 2 * B_ * H_ + 255) / 256, 256, 0, stream>>>(
        h0in, c0in, bih0, bhh0, bih1, bhh1, bias0, bias1,
        h0A, h0B, h1A, h1B, c0, c1, h1f);

    for (int p = 0; p <= S_; ++p) {
        const u16* h0r = (p & 1) ? h0B : h0A;
        u16*       h0w = (p & 1) ? h0A : h0B;
        const u16* h1r = (p & 1) ? h1B : h1A;
        u16*       h1w = (p & 1) ? h1A : h1B;
        phase_k<<<256, 256, 0, stream>>>(x, p, W0, W1, bias0, bias1,
                                         h0r, h0w, h1r, h1w, c0, c1, h1f,
                                         (p < S_) ? 1 : 0, (p >= 1) ? 1 : 0);
    }
    fc_k<<<(64000 + 255) / 256, 256, 0, stream>>>(h1f, Wfc, bfc, out);
}